// Round 4
// baseline (1586.771 us; speedup 1.0000x reference)
//
#include <hip/hip_runtime.h>
#include <math.h>

// DigitCaps dynamic routing. B=512, I=1152, K=8, C=10, D=16, 3 iters.
//
// R3 lesson: per-lane divergent W global reads (6x replicated, 10 lines/inst)
// made the kernel latency-bound (VALUBusy 10%). R4: W lives in REGISTERS
// (64 floats/lane, loaded once), b is STREAMED through the wave via LDS tiles.
//
// Lane map: lane = c + 10*dh + 20*i_sub (60 active; dh = d-half, i_sub picks
// one of 3 i per wave). Block = 4 waves = 12 i. Grid (96 i-chunks, 8 b-groups
// of 64). b processed in 4 sub-chunks of 16 with u/v staged in LDS.
// s accumulated in 3 per-i_sub LDS layers (no same-address atomic clash,
// c-rotated slots for bank spread), flushed via global f32 atomics into a
// 320 KB s buffer per pass; squash kernel finishes.

#define IC   12      // i per block
#define NIC  96      // 1152 / IC
#define NBG  8       // b-groups
#define BG   64      // b per block
#define BSUB 16      // b per sub-chunk
#define NSUB 4       // BG / BSUB
#define SL_PITCH 2568  // 16*160 + 8 pad (rotates banks per layer)

__device__ __forceinline__ float dot8(const float4 w0, const float4 w1,
                                      const float4 ua, const float4 ub) {
    return w0.x * ua.x + w0.y * ua.y + w0.z * ua.z + w0.w * ua.w
         + w1.x * ub.x + w1.y * ub.y + w1.z * ub.z + w1.w * ub.w;
}

template <int PASS>
__global__ __launch_bounds__(256, 3)
void pass_kernel(const float* __restrict__ u, const float* __restrict__ W,
                 const float* __restrict__ v0g, const float* __restrict__ v1g,
                 float* __restrict__ s_glob)
{
    __shared__ float u_t[BSUB * 96];        // [b][i_loc*8+k]
    __shared__ float v_t[BSUB * 240];       // [b][L*12 + d'] (L = c+10*dh)
    __shared__ float s_l[3 * SL_PITCH];     // per-i_sub layers [b*160 + slot]
    __shared__ float scr[4 * 3 * 12];       // softmax logit exchange [wv][i_sub][c]

    const int t    = threadIdx.x;
    const int lane = t & 63;
    const int wv   = t >> 6;
    int i_sub = lane / 20;                  // 0..3 (3 == idle lanes 60..63)
    const bool ok = (i_sub < 3);
    if (!ok) i_sub = 0;
    const int rem = lane % 20;
    const int dh  = rem / 10;
    const int c   = rem - dh * 10;
    const int L   = c + 10 * dh;
    const int i_loc = wv * 3 + i_sub;
    const int i     = blockIdx.x * IC + i_loc;
    const int b_base = blockIdx.y * BG;
    const int prt = c + 10 * (1 - dh) + 20 * i_sub;   // dh-partner lane
    const int sls = i_sub * SL_PITCH;

    // ---- W slice into registers: W[i, c, dh*8 .. dh*8+8, 0:8] = 64 floats ----
    const float4* Wp = (const float4*)(W + (((size_t)i * 10 + c) * 16 + dh * 8) * 8);
    float4 w[16];
    #pragma unroll
    for (int j = 0; j < 16; ++j) w[j] = Wp[j];

    #pragma unroll 1
    for (int scix = 0; scix < NSUB; ++scix) {
        const int b0 = b_base + scix * BSUB;

        // zero s layers
        for (int idx = t; idx < 3 * SL_PITCH; idx += 256) s_l[idx] = 0.0f;
        // stage u tile: 16 b x 96 floats (coalesced float4)
        for (int idx = t; idx < BSUB * 24; idx += 256) {
            int bl = idx / 24, f = idx - bl * 24;
            ((float4*)u_t)[bl * 24 + f] =
                *(const float4*)(u + ((size_t)(b0 + bl) * 1152 + blockIdx.x * IC) * 8 + f * 4);
        }
        if (PASS >= 1) {
            for (int idx = t; idx < BSUB * 160; idx += 256) {
                int bl = idx / 160, cd = idx - bl * 160;
                int cc = cd >> 4, d = cd & 15, dhh = d >> 3, dp = d & 7;
                float vv = v0g[(size_t)(b0 + bl) * 160 + cd];
                if (PASS >= 2) vv += v1g[(size_t)(b0 + bl) * 160 + cd];
                v_t[bl * 240 + (cc + 10 * dhh) * 12 + dp] = vv;
            }
        }
        __syncthreads();

        #pragma unroll 1
        for (int bl = 0; bl < BSUB; ++bl) {
            const float4* up = (const float4*)&u_t[bl * 96 + i_loc * 8];
            const float4 ua = up[0], ub = up[1];

            float h[8];
            #pragma unroll
            for (int d = 0; d < 8; ++d) h[d] = dot8(w[2 * d], w[2 * d + 1], ua, ub);

            float coef;
            if (PASS == 0) {
                coef = 0.1f;
            } else {
                const float4* vp = (const float4*)&v_t[bl * 240 + L * 12];
                const float4 va = vp[0], vb = vp[1];
                float lg = h[0] * va.x + h[1] * va.y + h[2] * va.z + h[3] * va.w
                         + h[4] * vb.x + h[5] * vb.y + h[6] * vb.z + h[7] * vb.w;
                lg += __shfl(lg, prt);                 // sum both d-halves
                if (ok && dh == 0) scr[(wv * 3 + i_sub) * 12 + c] = lg;
                const float4 lj0 = *(const float4*)&scr[(wv * 3 + i_sub) * 12 + 0];
                const float4 lj1 = *(const float4*)&scr[(wv * 3 + i_sub) * 12 + 4];
                const float2 lj2 = *(const float2*)&scr[(wv * 3 + i_sub) * 12 + 8];
                float m = fmaxf(fmaxf(fmaxf(lj0.x, lj0.y), fmaxf(lj0.z, lj0.w)),
                                fmaxf(fmaxf(fmaxf(lj1.x, lj1.y), fmaxf(lj1.z, lj1.w)),
                                      fmaxf(lj2.x, lj2.y)));
                float sum = __expf(lj0.x - m) + __expf(lj0.y - m) + __expf(lj0.z - m)
                          + __expf(lj0.w - m) + __expf(lj1.x - m) + __expf(lj1.y - m)
                          + __expf(lj1.z - m) + __expf(lj1.w - m) + __expf(lj2.x - m)
                          + __expf(lj2.y - m);
                coef = __expf(lg - m) / sum;
            }

            if (ok) {
#if defined(__HIP_DEVICE_COMPILE__)
                #pragma unroll
                for (int j = 0; j < 8; ++j) {
                    const int slot = L * 8 + ((j + c) & 7);   // c-rotation: bank spread
                    unsafeAtomicAdd(&s_l[sls + bl * 160 + slot], coef * h[j]);
                }
#endif
            }
        }
        __syncthreads();

        // flush sub-chunk: sum 3 layers, de-rotate, global atomic add
        for (int idx = t; idx < BSUB * 160; idx += 256) {
            int bl = idx / 160, cd = idx - bl * 160;
            int cc = cd >> 4, d = cd & 15, dhh = d >> 3, dp = d & 7;
            const int slot = bl * 160 + (cc + 10 * dhh) * 8 + ((dp + cc) & 7);
            float val = s_l[slot] + s_l[SL_PITCH + slot] + s_l[2 * SL_PITCH + slot];
#if defined(__HIP_DEVICE_COMPILE__)
            unsafeAtomicAdd(&s_glob[(size_t)(b0 + bl) * 160 + cd], val);
#endif
        }
        __syncthreads();
    }
}

// Squash: one thread per (b,c) row.
__global__ void squash_only(const float* __restrict__ s, float* __restrict__ vout)
{
    int r = blockIdx.x * 256 + threadIdx.x;
    if (r >= 512 * 10) return;
    const float* sp = s + (size_t)r * 16;
    float sv[16];
    float ns = 0.0f;
    #pragma unroll
    for (int d = 0; d < 16; ++d) {
        float x = sp[d];
        sv[d] = x;
        ns += x * x;
    }
    float scale = ns / ((1.0f + ns) * (sqrtf(ns) + 1e-8f));
    float* o = vout + (size_t)r * 16;
    #pragma unroll
    for (int d = 0; d < 16; ++d) o[d] = sv[d] * scale;
}

extern "C" void kernel_launch(void* const* d_in, const int* in_sizes, int n_in,
                              void* d_out, int out_size, void* d_ws, size_t ws_size,
                              hipStream_t stream)
{
    const float* u = (const float*)d_in[0];   // [512,1152,8]
    const float* W = (const float*)d_in[1];   // [1152,10,16,8]
    float* out = (float*)d_out;               // [512,10,16]

    float* v0 = (float*)d_ws;                 // 81920 f32
    float* v1 = v0 + 81920;
    float* s0 = v1 + 81920;
    float* s1 = s0 + 81920;
    float* s2 = s1 + 81920;

    // zero the three s accumulators (one contiguous memset)
    hipMemsetAsync(s0, 0, (size_t)3 * 81920 * sizeof(float), stream);

    dim3 grid(NIC, NBG);
    dim3 blk(256);

    pass_kernel<0><<<grid, blk, 0, stream>>>(u, W, nullptr, nullptr, s0);
    squash_only<<<20, 256, 0, stream>>>(s0, v0);
    pass_kernel<1><<<grid, blk, 0, stream>>>(u, W, v0, nullptr, s1);
    squash_only<<<20, 256, 0, stream>>>(s1, v1);
    pass_kernel<2><<<grid, blk, 0, stream>>>(u, W, v0, v1, s2);
    squash_only<<<20, 256, 0, stream>>>(s2, out);
}

// Round 5
// 434.638 us; speedup vs baseline: 3.6508x; 3.6508x over previous
//
#include <hip/hip_runtime.h>
#include <math.h>

// DigitCaps dynamic routing. B=512, I=1152, K=8, C=10, D=16, 3 iters.
//
// R1-R4 lesson: every fused design was latency-bound on serial LDS chains
// (spill / CSE-spill / divergent W / LDS softmax round-trips). R5: materialize
// u_hat (377 MB f32) in ws, then each routing pass is a single coalesced
// stream where a WAVE holds one (b,i) row of 160 floats in registers
// (lane = cd-quad, 40 active lanes). Softmax is register+shuffle only
// (logits bounded => no max subtraction). No LDS, no barriers in any hot loop.
//
// Producer fuses pass 0 (coef == 0.1): s0 = sum_i u_hat accumulated in regs,
// flushed with global f32 atomics. W row lives in registers, 4 b per wave.
//
// ws branches: f32 u_hat (379 MB) -> bf16 u_hat (190 MB) -> R3-style fallback.

#define UHQ 40          // float4 quads per (b,i) row (160 floats)
#define K1_CH 48        // producer i-chunks (24 i each), 4 b per wave
#define K2_CH 12        // pass-kernel i-chunks per b (96 i each)

__device__ __forceinline__ float dot8(const float4 w0, const float4 w1,
                                      const float4 ua, const float4 ub) {
    return w0.x*ua.x + w0.y*ua.y + w0.z*ua.z + w0.w*ua.w
         + w1.x*ub.x + w1.y*ub.y + w1.z*ub.z + w1.w*ub.w;
}

__device__ __forceinline__ unsigned short bf16_rn(float x) {
    unsigned u = __float_as_uint(x);
    u += 0x7FFFu + ((u >> 16) & 1u);
    return (unsigned short)(u >> 16);
}
__device__ __forceinline__ float bf16_to_f(unsigned short h) {
    return __uint_as_float(((unsigned)h) << 16);
}

// ---------------- Producer: u_hat + fused pass-0 sum ----------------
template <int BF16>
__global__ __launch_bounds__(256, 4)
void produce_uhat(const float* __restrict__ u, const float* __restrict__ W,
                  float* __restrict__ uhat_f, unsigned short* __restrict__ uhat_h,
                  float* __restrict__ s0)
{
    const int t = threadIdx.x, lane = t & 63, wv = t >> 6;
    const int gid = blockIdx.x * 4 + wv;
    const int bq  = gid / K1_CH;          // 0..127
    const int ch  = gid - bq * K1_CH;     // 0..47
    const int b0  = bq * 4;
    const int i0  = ch * 24;
    const int q   = lane;
    const bool act = (q < UHQ);

    float4 acc[4];
    #pragma unroll
    for (int bb = 0; bb < 4; ++bb) acc[bb] = make_float4(0.f, 0.f, 0.f, 0.f);

    for (int ii = 0; ii < 24; ++ii) {
        const int i = i0 + ii;
        float4 w4[8];
        if (act) {
            const float4* wp = (const float4*)(W + (size_t)i * 1280 + q * 32);
            #pragma unroll
            for (int j = 0; j < 8; ++j) w4[j] = wp[j];
        }
        #pragma unroll
        for (int bb = 0; bb < 4; ++bb) {
            const int b = b0 + bb;
            const float4* up = (const float4*)(u + ((size_t)b * 1152 + i) * 8);
            const float4 ua = up[0], ub = up[1];   // wave-uniform broadcast
            if (act) {
                float4 uh;
                uh.x = dot8(w4[0], w4[1], ua, ub);
                uh.y = dot8(w4[2], w4[3], ua, ub);
                uh.z = dot8(w4[4], w4[5], ua, ub);
                uh.w = dot8(w4[6], w4[7], ua, ub);
                acc[bb].x += uh.x; acc[bb].y += uh.y;
                acc[bb].z += uh.z; acc[bb].w += uh.w;
                const size_t qi = ((size_t)b * 1152 + i) * UHQ + q;
                if (BF16) {
                    ushort4 h;
                    h.x = bf16_rn(uh.x); h.y = bf16_rn(uh.y);
                    h.z = bf16_rn(uh.z); h.w = bf16_rn(uh.w);
                    ((ushort4*)uhat_h)[qi] = h;
                } else {
                    ((float4*)uhat_f)[qi] = uh;
                }
            }
        }
    }
    if (act) {
#if defined(__HIP_DEVICE_COMPILE__)
        #pragma unroll
        for (int bb = 0; bb < 4; ++bb) {
            float* sp = s0 + (size_t)(b0 + bb) * 160 + q * 4;
            unsafeAtomicAdd(sp + 0, acc[bb].x);
            unsafeAtomicAdd(sp + 1, acc[bb].y);
            unsafeAtomicAdd(sp + 2, acc[bb].z);
            unsafeAtomicAdd(sp + 3, acc[bb].w);
        }
#endif
    }
}

// ---------------- Routing pass: stream u_hat once ----------------
template <int PASS, int BF16>
__global__ __launch_bounds__(256, 8)
void route_pass(const float* __restrict__ uhat_f,
                const unsigned short* __restrict__ uhat_h,
                const float* __restrict__ v0g, const float* __restrict__ v1g,
                float* __restrict__ sg)
{
    const int t = threadIdx.x, lane = t & 63, wv = t >> 6;
    const int gid = blockIdx.x * 4 + wv;
    const int b   = gid / K2_CH;          // 0..511
    const int ch  = gid - b * K2_CH;      // 0..11
    const int i0  = ch * 96;
    const int q   = lane;
    const bool act = (q < UHQ);

    float4 va = make_float4(0.f, 0.f, 0.f, 0.f);
    if (act) {
        va = ((const float4*)v0g)[(size_t)b * UHQ + q];
        if (PASS == 2) {
            const float4 vb = ((const float4*)v1g)[(size_t)b * UHQ + q];
            va.x += vb.x; va.y += vb.y; va.z += vb.z; va.w += vb.w;
        }
    }
    float4 sacc = make_float4(0.f, 0.f, 0.f, 0.f);

    for (int ii = 0; ii < 96; ++ii) {
        const int i = i0 + ii;
        float4 uh = make_float4(0.f, 0.f, 0.f, 0.f);
        if (act) {
            const size_t qi = ((size_t)b * 1152 + i) * UHQ + q;
            if (BF16) {
                const ushort4 h = ((const ushort4*)uhat_h)[qi];
                uh.x = bf16_to_f(h.x); uh.y = bf16_to_f(h.y);
                uh.z = bf16_to_f(h.z); uh.w = bf16_to_f(h.w);
            } else {
                uh = ((const float4*)uhat_f)[qi];
            }
        }
        // logit for this lane's c (= q>>2): 4-lane segmented reduction
        float pd = uh.x*va.x + uh.y*va.y + uh.z*va.z + uh.w*va.w;
        pd += __shfl_xor(pd, 1);
        pd += __shfl_xor(pd, 2);
        // softmax without max-subtraction (|logit| bounded ~6)
        const float e = __expf(pd);
        float sum = 0.0f;
        #pragma unroll
        for (int cc = 0; cc < 10; ++cc) sum += __shfl(e, 4 * cc);
        const float coef = e / sum;
        sacc.x += coef * uh.x; sacc.y += coef * uh.y;
        sacc.z += coef * uh.z; sacc.w += coef * uh.w;
    }
    if (act) {
#if defined(__HIP_DEVICE_COMPILE__)
        float* sp = sg + (size_t)b * 160 + q * 4;
        unsafeAtomicAdd(sp + 0, sacc.x);
        unsafeAtomicAdd(sp + 1, sacc.y);
        unsafeAtomicAdd(sp + 2, sacc.z);
        unsafeAtomicAdd(sp + 3, sacc.w);
#endif
    }
}

// ---------------- squash with scale ----------------
__global__ void squash_scale(const float* __restrict__ s, float* __restrict__ vout,
                             float scale)
{
    int r = blockIdx.x * 256 + threadIdx.x;
    if (r >= 512 * 10) return;
    const float* sp = s + (size_t)r * 16;
    float sv[16];
    float ns = 0.0f;
    #pragma unroll
    for (int d = 0; d < 16; ++d) {
        float x = sp[d] * scale;
        sv[d] = x;
        ns += x * x;
    }
    float sc = ns / ((1.0f + ns) * (sqrtf(ns) + 1e-8f));
    float* o = vout + (size_t)r * 16;
    #pragma unroll
    for (int d = 0; d < 16; ++d) o[d] = sv[d] * sc;
}

// ---------------- R3-style fallback (tiny ws): thread owns (b,c) ----------------
template <int PASS>
__global__ __launch_bounds__(256, 4)
void pass_fb(const float* __restrict__ u, const float* __restrict__ W,
             const float* __restrict__ v0g, const float* __restrict__ v1g,
             float* __restrict__ s_atomic)
{
    const int t    = threadIdx.x;
    const int lane = t & 63;
    const int wv   = t >> 6;
    const int bsub = lane / 10;
    const int c    = lane - bsub * 10;
    const bool lane_ok = (bsub < 6);
    const int b    = blockIdx.y * 24 + wv * 6 + bsub;
    const bool valid = lane_ok && (b < 512);
    const int bc   = valid ? b : 511;
    const int base = lane_ok ? bsub * 10 : 0;
    const int i0   = blockIdx.x * 24;

    float v[16];
    #pragma unroll
    for (int d = 0; d < 16; ++d) v[d] = 0.0f;
    if (PASS >= 1) {
        const float* vp = v0g + ((size_t)bc * 10 + c) * 16;
        #pragma unroll
        for (int d = 0; d < 16; ++d) v[d] = vp[d];
        if (PASS >= 2) {
            const float* vq = v1g + ((size_t)bc * 10 + c) * 16;
            #pragma unroll
            for (int d = 0; d < 16; ++d) v[d] += vq[d];
        }
    }

    float s_acc[16];
    #pragma unroll
    for (int d = 0; d < 16; ++d) s_acc[d] = 0.0f;

    for (int ii = 0; ii < 24; ++ii) {
        const int i = i0 + ii;
        const float4* up = (const float4*)(u + ((size_t)bc * 1152 + i) * 8);
        const float4 ua = up[0];
        const float4 ub = up[1];
        const float* Wp = W + ((size_t)i * 10 + c) * 128;

        float h[16];
        #pragma unroll
        for (int d = 0; d < 16; ++d) {
            const float4* wp = (const float4*)(Wp + d * 8);
            h[d] = dot8(wp[0], wp[1], ua, ub);
        }

        if (PASS == 0) {
            #pragma unroll
            for (int d = 0; d < 16; ++d) s_acc[d] += h[d];
        } else {
            float lg = 0.0f;
            #pragma unroll
            for (int d = 0; d < 16; ++d) lg += h[d] * v[d];
            float lj[10];
            #pragma unroll
            for (int j = 0; j < 10; ++j) lj[j] = __shfl(lg, base + j);
            float m = lj[0];
            #pragma unroll
            for (int j = 1; j < 10; ++j) m = fmaxf(m, lj[j]);
            float sum = 0.0f;
            #pragma unroll
            for (int j = 0; j < 10; ++j) sum += __expf(lj[j] - m);
            const float coef = __expf(lg - m) / sum;
            #pragma unroll
            for (int d = 0; d < 16; ++d) s_acc[d] += coef * h[d];
        }
    }
    if (PASS == 0) {
        #pragma unroll
        for (int d = 0; d < 16; ++d) s_acc[d] *= 0.1f;
    }
    if (valid) {
#if defined(__HIP_DEVICE_COMPILE__)
        #pragma unroll
        for (int d = 0; d < 16; ++d)
            unsafeAtomicAdd(&s_atomic[((size_t)b * 10 + c) * 16 + d], s_acc[d]);
#endif
    }
}

extern "C" void kernel_launch(void* const* d_in, const int* in_sizes, int n_in,
                              void* d_out, int out_size, void* d_ws, size_t ws_size,
                              hipStream_t stream)
{
    const float* u = (const float*)d_in[0];   // [512,1152,8]
    const float* W = (const float*)d_in[1];   // [1152,10,16,8]
    float* out = (float*)d_out;               // [512,10,16]

    float* v0 = (float*)d_ws;
    float* v1 = v0 + 81920;
    float* s0 = v1 + 81920;
    float* s1 = s0 + 81920;
    float* s2 = s1 + 81920;
    char*  uh = (char*)(s2 + 81920);

    const size_t head   = (size_t)5 * 81920 * sizeof(float);       // 1.64 MB
    const size_t uh_f32 = (size_t)512 * 1152 * 160 * 4;            // 377.5 MB
    const size_t uh_b16 = uh_f32 / 2;                              // 188.7 MB

    hipMemsetAsync(s0, 0, (size_t)3 * 81920 * sizeof(float), stream);

    dim3 blk(256);

    if (ws_size >= head + uh_f32) {
        produce_uhat<0><<<1536, blk, 0, stream>>>(u, W, (float*)uh, nullptr, s0);
        squash_scale<<<20, blk, 0, stream>>>(s0, v0, 0.1f);
        route_pass<1, 0><<<1536, blk, 0, stream>>>((float*)uh, nullptr, v0, nullptr, s1);
        squash_scale<<<20, blk, 0, stream>>>(s1, v1, 1.0f);
        route_pass<2, 0><<<1536, blk, 0, stream>>>((float*)uh, nullptr, v0, v1, s2);
        squash_scale<<<20, blk, 0, stream>>>(s2, out, 1.0f);
    } else if (ws_size >= head + uh_b16) {
        unsigned short* uhh = (unsigned short*)uh;
        produce_uhat<1><<<1536, blk, 0, stream>>>(u, W, nullptr, uhh, s0);
        squash_scale<<<20, blk, 0, stream>>>(s0, v0, 0.1f);
        route_pass<1, 1><<<1536, blk, 0, stream>>>(nullptr, uhh, v0, nullptr, s1);
        squash_scale<<<20, blk, 0, stream>>>(s1, v1, 1.0f);
        route_pass<2, 1><<<1536, blk, 0, stream>>>(nullptr, uhh, v0, v1, s2);
        squash_scale<<<20, blk, 0, stream>>>(s2, out, 1.0f);
    } else {
        // tiny-ws fallback (R3-style, ~1.4 ms)
        dim3 grid(48, 22);
        pass_fb<0><<<grid, blk, 0, stream>>>(u, W, nullptr, nullptr, s0);
        squash_scale<<<20, blk, 0, stream>>>(s0, v0, 1.0f);
        pass_fb<1><<<grid, blk, 0, stream>>>(u, W, v0, nullptr, s1);
        squash_scale<<<20, blk, 0, stream>>>(s1, v1, 1.0f);
        pass_fb<2><<<grid, blk, 0, stream>>>(u, W, v0, v1, s2);
        squash_scale<<<20, blk, 0, stream>>>(s2, out, 1.0f);
    }
}

// Round 6
// 333.180 us; speedup vs baseline: 4.7625x; 1.3045x over previous
//
#include <hip/hip_runtime.h>
#include <math.h>

// DigitCaps dynamic routing. B=512, I=1152, K=8, C=10, D=16, 3 iters.
//
// R5 structure (3.2x win): materialize bf16 u_hat (189 MB) in ws; each routing
// pass streams it once; wave owns a (b,i) row (lane = cd-quad, 40/64 active);
// softmax fully in-register. R6 fixes the three measured stalls:
//  1. W pre-transposed to W_t[i][j][q] -> producer W loads are 640 B
//     contiguous per instruction (R5: 40 cache lines per load, 200 us, 27% VALU).
//  2. route_pass softmax: masked xor-butterfly (4 shfl) instead of 10
//     sequential broadcast shfls.
//  3. route_pass 2-wide i-unroll: independent chains hide shfl/exp latency.

#define UHQ 40          // float4/ushort4 quads per (b,i) row (160 elems)
#define K1_CH 48        // producer i-chunks (24 i each), 4 b per wave
#define K2_CH 12        // route i-chunks per b (96 i each)

__device__ __forceinline__ float dot8(const float4 w0, const float4 w1,
                                      const float4 ua, const float4 ub) {
    return w0.x*ua.x + w0.y*ua.y + w0.z*ua.z + w0.w*ua.w
         + w1.x*ub.x + w1.y*ub.y + w1.z*ub.z + w1.w*ub.w;
}

__device__ __forceinline__ unsigned short bf16_rn(float x) {
    unsigned u = __float_as_uint(x);
    u += 0x7FFFu + ((u >> 16) & 1u);
    return (unsigned short)(u >> 16);
}
__device__ __forceinline__ float bf16_to_f(unsigned short h) {
    return __uint_as_float(((unsigned)h) << 16);
}

// ---------------- W transpose: W[i][c][d][k] -> W_t[i][j][q] (float4 units) ----------------
// Producer lane q needs floats [q*32 .. q*32+32) of row i, as 8 float4 (j=0..7).
// W_t stores quad (i,q,j) at float4 index i*320 + j*40 + q  => lane-consecutive.
__global__ void transpose_W(const float4* __restrict__ W4, float4* __restrict__ Wt4)
{
    int tid = blockIdx.x * 256 + threadIdx.x;
    if (tid >= 1152 * 320) return;
    int i = tid / 320, r = tid - i * 320;
    int q = r >> 3, j = r & 7;
    Wt4[i * 320 + j * 40 + q] = W4[tid];   // read coalesced, scatter within 5 KB row
}

// ---------------- Producer (coalesced W_t): u_hat bf16 + fused pass-0 sum ----------------
__global__ __launch_bounds__(256, 4)
void produce_uhat_t(const float* __restrict__ u, const float* __restrict__ Wt,
                    unsigned short* __restrict__ uhat_h, float* __restrict__ s0)
{
    const int t = threadIdx.x, lane = t & 63, wv = t >> 6;
    const int gid = blockIdx.x * 4 + wv;
    const int bq  = gid / K1_CH;          // 0..127
    const int ch  = gid - bq * K1_CH;     // 0..47
    const int b0  = bq * 4;
    const int i0  = ch * 24;
    const int q   = lane;
    const bool act = (q < UHQ);

    float4 acc[4];
    #pragma unroll
    for (int bb = 0; bb < 4; ++bb) acc[bb] = make_float4(0.f, 0.f, 0.f, 0.f);

    for (int ii = 0; ii < 24; ++ii) {
        const int i = i0 + ii;
        float4 w4[8];
        if (act) {
            const float4* wb = (const float4*)(Wt + (size_t)i * 1280);
            #pragma unroll
            for (int j = 0; j < 8; ++j) w4[j] = wb[j * 40 + q];   // 640 B contiguous
        }
        #pragma unroll
        for (int bb = 0; bb < 4; ++bb) {
            const int b = b0 + bb;
            const float4* up = (const float4*)(u + ((size_t)b * 1152 + i) * 8);
            const float4 ua = up[0], ub = up[1];   // wave-uniform broadcast
            if (act) {
                float4 uh;
                uh.x = dot8(w4[0], w4[1], ua, ub);
                uh.y = dot8(w4[2], w4[3], ua, ub);
                uh.z = dot8(w4[4], w4[5], ua, ub);
                uh.w = dot8(w4[6], w4[7], ua, ub);
                acc[bb].x += uh.x; acc[bb].y += uh.y;
                acc[bb].z += uh.z; acc[bb].w += uh.w;
                ushort4 h;
                h.x = bf16_rn(uh.x); h.y = bf16_rn(uh.y);
                h.z = bf16_rn(uh.z); h.w = bf16_rn(uh.w);
                ((ushort4*)uhat_h)[((size_t)b * 1152 + i) * UHQ + q] = h;
            }
        }
    }
    if (act) {
#if defined(__HIP_DEVICE_COMPILE__)
        #pragma unroll
        for (int bb = 0; bb < 4; ++bb) {
            float* sp = s0 + (size_t)(b0 + bb) * 160 + q * 4;
            unsafeAtomicAdd(sp + 0, acc[bb].x);
            unsafeAtomicAdd(sp + 1, acc[bb].y);
            unsafeAtomicAdd(sp + 2, acc[bb].z);
            unsafeAtomicAdd(sp + 3, acc[bb].w);
        }
#endif
    }
}

// ---------------- Producer fallback (R5 divergent-W version, no W_t buffer) ----------------
__global__ __launch_bounds__(256, 4)
void produce_uhat_div(const float* __restrict__ u, const float* __restrict__ W,
                      unsigned short* __restrict__ uhat_h, float* __restrict__ s0)
{
    const int t = threadIdx.x, lane = t & 63, wv = t >> 6;
    const int gid = blockIdx.x * 4 + wv;
    const int bq  = gid / K1_CH;
    const int ch  = gid - bq * K1_CH;
    const int b0  = bq * 4;
    const int i0  = ch * 24;
    const int q   = lane;
    const bool act = (q < UHQ);

    float4 acc[4];
    #pragma unroll
    for (int bb = 0; bb < 4; ++bb) acc[bb] = make_float4(0.f, 0.f, 0.f, 0.f);

    for (int ii = 0; ii < 24; ++ii) {
        const int i = i0 + ii;
        float4 w4[8];
        if (act) {
            const float4* wp = (const float4*)(W + (size_t)i * 1280 + q * 32);
            #pragma unroll
            for (int j = 0; j < 8; ++j) w4[j] = wp[j];
        }
        #pragma unroll
        for (int bb = 0; bb < 4; ++bb) {
            const int b = b0 + bb;
            const float4* up = (const float4*)(u + ((size_t)b * 1152 + i) * 8);
            const float4 ua = up[0], ub = up[1];
            if (act) {
                float4 uh;
                uh.x = dot8(w4[0], w4[1], ua, ub);
                uh.y = dot8(w4[2], w4[3], ua, ub);
                uh.z = dot8(w4[4], w4[5], ua, ub);
                uh.w = dot8(w4[6], w4[7], ua, ub);
                acc[bb].x += uh.x; acc[bb].y += uh.y;
                acc[bb].z += uh.z; acc[bb].w += uh.w;
                ushort4 h;
                h.x = bf16_rn(uh.x); h.y = bf16_rn(uh.y);
                h.z = bf16_rn(uh.z); h.w = bf16_rn(uh.w);
                ((ushort4*)uhat_h)[((size_t)b * 1152 + i) * UHQ + q] = h;
            }
        }
    }
    if (act) {
#if defined(__HIP_DEVICE_COMPILE__)
        #pragma unroll
        for (int bb = 0; bb < 4; ++bb) {
            float* sp = s0 + (size_t)(b0 + bb) * 160 + q * 4;
            unsafeAtomicAdd(sp + 0, acc[bb].x);
            unsafeAtomicAdd(sp + 1, acc[bb].y);
            unsafeAtomicAdd(sp + 2, acc[bb].z);
            unsafeAtomicAdd(sp + 3, acc[bb].w);
        }
#endif
    }
}

// ---------------- Routing pass: stream u_hat once, 2-wide unroll ----------------
template <int PASS>
__global__ __launch_bounds__(256, 8)
void route_pass(const unsigned short* __restrict__ uhat_h,
                const float* __restrict__ v0g, const float* __restrict__ v1g,
                float* __restrict__ sg)
{
    const int t = threadIdx.x, lane = t & 63, wv = t >> 6;
    const int gid = blockIdx.x * 4 + wv;
    const int b   = gid / K2_CH;          // 0..511
    const int ch  = gid - b * K2_CH;      // 0..11
    const int i0  = ch * 96;
    const int q   = lane;
    const bool act = (q < UHQ);

    float4 va = make_float4(0.f, 0.f, 0.f, 0.f);
    if (act) {
        va = ((const float4*)v0g)[(size_t)b * UHQ + q];
        if (PASS == 2) {
            const float4 vb = ((const float4*)v1g)[(size_t)b * UHQ + q];
            va.x += vb.x; va.y += vb.y; va.z += vb.z; va.w += vb.w;
        }
    }
    float4 sacc = make_float4(0.f, 0.f, 0.f, 0.f);

    const ushort4* up = (const ushort4*)uhat_h;

    for (int ii = 0; ii < 96; ii += 2) {
        const size_t qi = ((size_t)b * 1152 + i0 + ii) * UHQ + q;
        float4 uh0 = make_float4(0.f, 0.f, 0.f, 0.f);
        float4 uh1 = make_float4(0.f, 0.f, 0.f, 0.f);
        if (act) {
            const ushort4 h0 = up[qi];
            const ushort4 h1 = up[qi + UHQ];
            uh0.x = bf16_to_f(h0.x); uh0.y = bf16_to_f(h0.y);
            uh0.z = bf16_to_f(h0.z); uh0.w = bf16_to_f(h0.w);
            uh1.x = bf16_to_f(h1.x); uh1.y = bf16_to_f(h1.y);
            uh1.z = bf16_to_f(h1.z); uh1.w = bf16_to_f(h1.w);
        }
        // per-c logit: 4-lane segmented reduction (two independent chains)
        float p0 = uh0.x*va.x + uh0.y*va.y + uh0.z*va.z + uh0.w*va.w;
        float p1 = uh1.x*va.x + uh1.y*va.y + uh1.z*va.z + uh1.w*va.w;
        p0 += __shfl_xor(p0, 1);  p1 += __shfl_xor(p1, 1);
        p0 += __shfl_xor(p0, 2);  p1 += __shfl_xor(p1, 2);
        // softmax, no max-subtraction (|logit| < ~0.5); mask inactive lanes
        const float e0 = act ? __expf(p0) : 0.0f;
        const float e1 = act ? __expf(p1) : 0.0f;
        float s0v = e0, s1v = e1;
        // xor-butterfly over strides 4..32: every lane gets sum over the 10 c-groups
        s0v += __shfl_xor(s0v, 4);   s1v += __shfl_xor(s1v, 4);
        s0v += __shfl_xor(s0v, 8);   s1v += __shfl_xor(s1v, 8);
        s0v += __shfl_xor(s0v, 16);  s1v += __shfl_xor(s1v, 16);
        s0v += __shfl_xor(s0v, 32);  s1v += __shfl_xor(s1v, 32);
        const float c0 = e0 / s0v;
        const float c1 = e1 / s1v;
        sacc.x += c0 * uh0.x + c1 * uh1.x;
        sacc.y += c0 * uh0.y + c1 * uh1.y;
        sacc.z += c0 * uh0.z + c1 * uh1.z;
        sacc.w += c0 * uh0.w + c1 * uh1.w;
    }
    if (act) {
#if defined(__HIP_DEVICE_COMPILE__)
        float* sp = sg + (size_t)b * 160 + q * 4;
        unsafeAtomicAdd(sp + 0, sacc.x);
        unsafeAtomicAdd(sp + 1, sacc.y);
        unsafeAtomicAdd(sp + 2, sacc.z);
        unsafeAtomicAdd(sp + 3, sacc.w);
#endif
    }
}

// ---------------- squash with pre-scale ----------------
__global__ void squash_scale(const float* __restrict__ s, float* __restrict__ vout,
                             float scale)
{
    int r = blockIdx.x * 256 + threadIdx.x;
    if (r >= 512 * 10) return;
    const float* sp = s + (size_t)r * 16;
    float sv[16];
    float ns = 0.0f;
    #pragma unroll
    for (int d = 0; d < 16; ++d) {
        float x = sp[d] * scale;
        sv[d] = x;
        ns += x * x;
    }
    float sc = ns / ((1.0f + ns) * (sqrtf(ns) + 1e-8f));
    float* o = vout + (size_t)r * 16;
    #pragma unroll
    for (int d = 0; d < 16; ++d) o[d] = sv[d] * sc;
}

// ---------------- tiny-ws fallback (R3-style): thread owns (b,c) ----------------
template <int PASS>
__global__ __launch_bounds__(256, 4)
void pass_fb(const float* __restrict__ u, const float* __restrict__ W,
             const float* __restrict__ v0g, const float* __restrict__ v1g,
             float* __restrict__ s_atomic)
{
    const int t    = threadIdx.x;
    const int lane = t & 63;
    const int wv   = t >> 6;
    const int bsub = lane / 10;
    const int c    = lane - bsub * 10;
    const bool lane_ok = (bsub < 6);
    const int b    = blockIdx.y * 24 + wv * 6 + bsub;
    const bool valid = lane_ok && (b < 512);
    const int bc   = valid ? b : 511;
    const int base = lane_ok ? bsub * 10 : 0;
    const int i0   = blockIdx.x * 24;

    float v[16];
    #pragma unroll
    for (int d = 0; d < 16; ++d) v[d] = 0.0f;
    if (PASS >= 1) {
        const float* vp = v0g + ((size_t)bc * 10 + c) * 16;
        #pragma unroll
        for (int d = 0; d < 16; ++d) v[d] = vp[d];
        if (PASS >= 2) {
            const float* vq = v1g + ((size_t)bc * 10 + c) * 16;
            #pragma unroll
            for (int d = 0; d < 16; ++d) v[d] += vq[d];
        }
    }

    float s_acc[16];
    #pragma unroll
    for (int d = 0; d < 16; ++d) s_acc[d] = 0.0f;

    for (int ii = 0; ii < 24; ++ii) {
        const int i = i0 + ii;
        const float4* up = (const float4*)(u + ((size_t)bc * 1152 + i) * 8);
        const float4 ua = up[0];
        const float4 ub = up[1];
        const float* Wp = W + ((size_t)i * 10 + c) * 128;

        float h[16];
        #pragma unroll
        for (int d = 0; d < 16; ++d) {
            const float4* wp = (const float4*)(Wp + d * 8);
            h[d] = dot8(wp[0], wp[1], ua, ub);
        }

        if (PASS == 0) {
            #pragma unroll
            for (int d = 0; d < 16; ++d) s_acc[d] += h[d];
        } else {
            float lg = 0.0f;
            #pragma unroll
            for (int d = 0; d < 16; ++d) lg += h[d] * v[d];
            float lj[10];
            #pragma unroll
            for (int j = 0; j < 10; ++j) lj[j] = __shfl(lg, base + j);
            float m = lj[0];
            #pragma unroll
            for (int j = 1; j < 10; ++j) m = fmaxf(m, lj[j]);
            float sum = 0.0f;
            #pragma unroll
            for (int j = 0; j < 10; ++j) sum += __expf(lj[j] - m);
            const float coef = __expf(lg - m) / sum;
            #pragma unroll
            for (int d = 0; d < 16; ++d) s_acc[d] += coef * h[d];
        }
    }
    if (PASS == 0) {
        #pragma unroll
        for (int d = 0; d < 16; ++d) s_acc[d] *= 0.1f;
    }
    if (valid) {
#if defined(__HIP_DEVICE_COMPILE__)
        #pragma unroll
        for (int d = 0; d < 16; ++d)
            unsafeAtomicAdd(&s_atomic[((size_t)b * 10 + c) * 16 + d], s_acc[d]);
#endif
    }
}

extern "C" void kernel_launch(void* const* d_in, const int* in_sizes, int n_in,
                              void* d_out, int out_size, void* d_ws, size_t ws_size,
                              hipStream_t stream)
{
    const float* u = (const float*)d_in[0];   // [512,1152,8]
    const float* W = (const float*)d_in[1];   // [1152,10,16,8]
    float* out = (float*)d_out;               // [512,10,16]

    float* v0 = (float*)d_ws;
    float* v1 = v0 + 81920;
    float* s0 = v1 + 81920;
    float* s1 = s0 + 81920;
    float* s2 = s1 + 81920;
    float* wt = s2 + 81920;                   // 1,474,560 f32 (5.9 MB)

    const size_t head   = (size_t)5 * 81920 * sizeof(float);          // 1.64 MB
    const size_t wtsz   = (size_t)1152 * 1280 * sizeof(float);        // 5.90 MB
    const size_t uh_b16 = (size_t)512 * 1152 * 160 * 2;               // 188.7 MB

    hipMemsetAsync(s0, 0, (size_t)3 * 81920 * sizeof(float), stream);

    dim3 blk(256);

    if (ws_size >= head + wtsz + uh_b16) {
        unsigned short* uhh = (unsigned short*)(wt + 1152 * 1280);
        transpose_W<<<1440, blk, 0, stream>>>((const float4*)W, (float4*)wt);
        produce_uhat_t<<<1536, blk, 0, stream>>>(u, wt, uhh, s0);
        squash_scale<<<20, blk, 0, stream>>>(s0, v0, 0.1f);
        route_pass<1><<<1536, blk, 0, stream>>>(uhh, v0, nullptr, s1);
        squash_scale<<<20, blk, 0, stream>>>(s1, v1, 1.0f);
        route_pass<2><<<1536, blk, 0, stream>>>(uhh, v0, v1, s2);
        squash_scale<<<20, blk, 0, stream>>>(s2, out, 1.0f);
    } else if (ws_size >= head + uh_b16) {
        unsigned short* uhh = (unsigned short*)wt;   // no W_t buffer
        produce_uhat_div<<<1536, blk, 0, stream>>>(u, W, uhh, s0);
        squash_scale<<<20, blk, 0, stream>>>(s0, v0, 0.1f);
        route_pass<1><<<1536, blk, 0, stream>>>(uhh, v0, nullptr, s1);
        squash_scale<<<20, blk, 0, stream>>>(s1, v1, 1.0f);
        route_pass<2><<<1536, blk, 0, stream>>>(uhh, v0, v1, s2);
        squash_scale<<<20, blk, 0, stream>>>(s2, out, 1.0f);
    } else {
        dim3 grid(48, 22);
        pass_fb<0><<<grid, blk, 0, stream>>>(u, W, nullptr, nullptr, s0);
        squash_scale<<<20, blk, 0, stream>>>(s0, v0, 1.0f);
        pass_fb<1><<<grid, blk, 0, stream>>>(u, W, v0, nullptr, s1);
        squash_scale<<<20, blk, 0, stream>>>(s1, v1, 1.0f);
        pass_fb<2><<<grid, blk, 0, stream>>>(u, W, v0, v1, s2);
        squash_scale<<<20, blk, 0, stream>>>(s2, out, 1.0f);
    }
}